// Round 5
// baseline (180.814 us; speedup 1.0000x reference)
//
#include <hip/hip_runtime.h>

#define SEQ  4096
#define DMODEL 1024
#define QTOT 16384           // B*S
#define QSCALE 0.18033688011112042f   // (1/sqrt(64)) * log2(e), folded into Q

typedef __bf16 bf16x8 __attribute__((ext_vector_type(8)));
typedef unsigned short u16x8 __attribute__((ext_vector_type(8)));
typedef float f32x4 __attribute__((ext_vector_type(4)));

// ---------- helpers ----------
static __device__ __forceinline__ unsigned short f2bfbits(float f) {
    unsigned int u = __builtin_bit_cast(unsigned int, f);
    unsigned int lsb = (u >> 16) & 1u;
    u += 0x7fffu + lsb;                      // round-to-nearest-even
    return (unsigned short)(u >> 16);
}

static __device__ __forceinline__ bf16x8 ld_frag(const unsigned short* p) {
    uint4 u = *reinterpret_cast<const uint4*>(p);
    return __builtin_bit_cast(bf16x8, u);
}

// ---------- kernel 1: weights -> bf16, pre-swizzled into MFMA fragment order ----------
__global__ void prep_weights(const float* __restrict__ Wq,
                             const float* __restrict__ Wk,
                             const float* __restrict__ Wv,
                             unsigned short* __restrict__ WtS) {
    int o = blockIdx.x * 256 + threadIdx.x;      // 192*1024 total
    int f = o >> 9, q = o & 511;
    int lane = q >> 3, j = q & 7;
    int kc = f / 12, nt = f - kc * 12;
    int n = nt * 16 + (lane & 15);
    int k = kc * 32 + (lane >> 4) * 8 + j;
    float v;
    if (n < 64)       v = Wq[k * 64 + n];
    else if (n < 128) v = Wk[k * 64 + (n - 64)];
    else              v = Wv[k * 64 + (n - 128)];
    WtS[o] = f2bfbits(v);
}

// ---------- kernel 2: QKV projection, coalesced LDS-staged emb ----------
// grid 512 x 256 thr (4 waves). Block = 32 tokens, N=192, full K (no K-split).
// wave w: m = w&1 (16-token M-subtile), nh = w>>1 (6-of-12 nt slice). acc[6].
// emb staged through LDS in 4 mega-steps of K=256 (contiguous 1KB row-chunks,
// XOR-swizzled LDS, T14 early-issue). Weights: contiguous fragment loads with
// s+1 prefetch pipeline.
__global__ __launch_bounds__(256) void proj_cs(
        const float* __restrict__ emb, const unsigned short* __restrict__ WtS,
        const float* __restrict__ bq, const float* __restrict__ bk,
        const float* __restrict__ bv,
        unsigned short* __restrict__ Qb, unsigned short* __restrict__ Kb,
        unsigned short* __restrict__ VT) {
    __shared__ __align__(16) unsigned short Et[2][32 * 256];   // 2 x 16 KB

    const int tid = threadIdx.x;
    const int w = tid >> 6, lane = tid & 63;
    const int c = lane & 15, qd = lane >> 4;
    const int m = w & 1, nh = w >> 1;
    const int mbase = blockIdx.x * 32;

    f32x4 acc[6];
#pragma unroll
    for (int i = 0; i < 6; i++) acc[i] = (f32x4){0.f, 0.f, 0.f, 0.f};

    // this wave's weight-fragment base: nt = nh*6 + jj
    const unsigned short* wpB = WtS + nh * 3072 + lane * 8;

    // ---- prologue: stage mega 0 (rows w*8..w*8+7, contiguous 1KB per row) ----
    {
        float4 g[8];
#pragma unroll
        for (int rr = 0; rr < 8; rr++)
            g[rr] = *reinterpret_cast<const float4*>(
                emb + (size_t)(mbase + w * 8 + rr) * DMODEL + lane * 4);
#pragma unroll
        for (int rr = 0; rr < 8; rr++) {
            int row = w * 8 + rr;
            ushort4 p;
            p.x = f2bfbits(g[rr].x); p.y = f2bfbits(g[rr].y);
            p.z = f2bfbits(g[rr].z); p.w = f2bfbits(g[rr].w);
            int off = (lane * 8) ^ ((row & 7) << 4);           // byte off in 512B row
            *reinterpret_cast<ushort4*>(
                reinterpret_cast<char*>(&Et[0][0]) + row * 512 + off) = p;
        }
    }

    // weight fragments for s=0
    bf16x8 wc[6];
#pragma unroll
    for (int jj = 0; jj < 6; jj++) wc[jj] = ld_frag(wpB + jj * 512);

    __syncthreads();

    int cur = 0;
    for (int mega = 0; mega < 4; mega++) {
        // issue next mega's global loads early (in flight during the MFMAs)
        float4 g[8];
        if (mega < 3) {
#pragma unroll
            for (int rr = 0; rr < 8; rr++)
                g[rr] = *reinterpret_cast<const float4*>(
                    emb + (size_t)(mbase + w * 8 + rr) * DMODEL
                        + (mega + 1) * 256 + lane * 4);
        }

        // hoist all 8 A-fragments for this mega (conflict-free swizzled reads)
        const char* Eb = reinterpret_cast<const char*>(&Et[cur][0]);
        bf16x8 aq[8];
#pragma unroll
        for (int ks = 0; ks < 8; ks++) {
            int off = (ks * 64 + qd * 16) ^ ((c & 7) << 4);
            aq[ks] = ld_frag(reinterpret_cast<const unsigned short*>(
                Eb + (m * 16 + c) * 512 + off));
        }

        // 8 K-steps; weight pipeline one step ahead
#pragma unroll
        for (int ks = 0; ks < 8; ks++) {
            int s = mega * 8 + ks;
            bf16x8 wn[6];
            if (s < 31) {
#pragma unroll
                for (int jj = 0; jj < 6; jj++)
                    wn[jj] = ld_frag(wpB + (s + 1) * 6144 + jj * 512);
            } else {
#pragma unroll
                for (int jj = 0; jj < 6; jj++) wn[jj] = wc[jj];
            }
#pragma unroll
            for (int jj = 0; jj < 6; jj++)
                acc[jj] = __builtin_amdgcn_mfma_f32_16x16x32_bf16(aq[ks], wc[jj], acc[jj], 0, 0, 0);
#pragma unroll
            for (int jj = 0; jj < 6; jj++) wc[jj] = wn[jj];
        }

        // convert + write next buffer (vmcnt wait lands here, after compute)
        if (mega < 3) {
#pragma unroll
            for (int rr = 0; rr < 8; rr++) {
                int row = w * 8 + rr;
                ushort4 p;
                p.x = f2bfbits(g[rr].x); p.y = f2bfbits(g[rr].y);
                p.z = f2bfbits(g[rr].z); p.w = f2bfbits(g[rr].w);
                int off = (lane * 8) ^ ((row & 7) << 4);
                *reinterpret_cast<ushort4*>(
                    reinterpret_cast<char*>(&Et[cur ^ 1][0]) + row * 512 + off) = p;
            }
        }
        __syncthreads();
        cur ^= 1;
    }

    // ---- epilogue: bias + scale + bf16 store ----
#pragma unroll
    for (int jj = 0; jj < 6; jj++) {
        int n = (nh * 6 + jj) * 16 + c;
        float bias = (n < 64) ? bq[n] : (n < 128) ? bk[n - 64] : bv[n - 128];
        float fac = (n < 64) ? QSCALE : 1.0f;
#pragma unroll
        for (int r = 0; r < 4; r++) {
            int token = mbase + m * 16 + qd * 4 + r;
            unsigned short bits = f2bfbits((acc[jj][r] + bias) * fac);
            if (n < 64)        Qb[(size_t)token * 64 + n] = bits;
            else if (n < 128)  Kb[(size_t)token * 64 + (n - 64)] = bits;
            else {
                int bb = token >> 12, ss = token & 4095;
                VT[((size_t)bb * 64 + (n - 128)) * SEQ + ss] = bits;
            }
        }
    }
}

// ---------- kernel 3: barrier-free flash attention (32-q blocks) ----------
// grid 512 blocks (4b x 128 q-blocks, XCD-pinned by b); 512 thr = 8 waves.
// Block owns 32 q-rows x full t; wave w owns t-slice [w*512, w*512+512).
// LDS 37.9 KB + ~96 VGPR -> 2 blocks/CU co-resident naturally = 4 waves/SIMD
// (2x round-3) to cover the K-load -> QK -> exp2 -> LDS -> PV chain.
// NOTE: launch_bounds kept at (512,2) — the (512,4)/128-VGPR cap correlated
// with both container failures this session and buys nothing (occupancy is
// LDS/VGPR-natural, not bound-forced).
// V-loads hoisted above the score phase; setprio(1) wraps MFMA clusters (T5).
__global__ __launch_bounds__(512, 2) void attn(
        const unsigned short* __restrict__ Qb, const unsigned short* __restrict__ Kb,
        const unsigned short* __restrict__ VT, float* __restrict__ out) {
    __shared__ __align__(16) unsigned short Pl[8][32 * 72];  // per-wave P [q][t]; aliased as reduce buf
    __shared__ float l_all[8][32];

    const int tid = threadIdx.x;
    const int w = tid >> 6, lane = tid & 63;
    const int c = lane & 15, qd = lane >> 4;
    // XCD pinning: blockIdx%8 = b*2 + (qblk&1)
    const int g3 = blockIdx.x & 7;
    const int b = g3 >> 1;
    const int qblk = ((blockIdx.x >> 3) << 1) | (g3 & 1);
    const int qbase = qblk * 32;
    const int tstart = w * 512;

    // Q A-fragments (shared across the 8 waves -> L1 broadcast), pre-scaled
    bf16x8 aq0[2], aq1[2];
#pragma unroll
    for (int qs = 0; qs < 2; qs++) {
        const unsigned short* Qp = Qb + ((size_t)(b << 12) + qbase + qs * 16 + c) * 64 + qd * 8;
        aq0[qs] = ld_frag(Qp);
        aq1[qs] = ld_frag(Qp + 32);
    }

    f32x4 acc[8];                                // [qsub][nt]
#pragma unroll
    for (int i = 0; i < 8; i++) acc[i] = (f32x4){0.f, 0.f, 0.f, 0.f};
    float lsum[2][4];
#pragma unroll
    for (int qs = 0; qs < 2; qs++)
#pragma unroll
        for (int r = 0; r < 4; r++) lsum[qs][r] = 0.f;

    unsigned short* myP = &Pl[w][0];

#pragma unroll 2
    for (int it = 0; it < 8; it++) {
        const int t0 = tstart + it * 64;
        const unsigned short* Kt = Kb + ((size_t)(b << 12) + t0) * 64;

        // K B-fragments straight from global
        bf16x8 bk0[4], bk1[4];
#pragma unroll
        for (int ts = 0; ts < 4; ts++) {
            bk0[ts] = ld_frag(Kt + (ts * 16 + c) * 64 + qd * 8);
            bk1[ts] = ld_frag(Kt + (ts * 16 + c) * 64 + 32 + qd * 8);
        }
        // V B-fragments issued EARLY: latency hides under QK MFMA + softmax VALU
        bf16x8 bv0[4], bv1[4];
#pragma unroll
        for (int nt = 0; nt < 4; nt++) {
            const unsigned short* Vp = VT + (((size_t)b * 64 + nt * 16 + c) << 12) + t0 + qd * 8;
            bv0[nt] = ld_frag(Vp);
            bv1[nt] = ld_frag(Vp + 32);
        }

        // scores -> exp2 -> P into per-wave LDS (no barrier)
#pragma unroll
        for (int qs = 0; qs < 2; qs++) {
            f32x4 sc[4];
            __builtin_amdgcn_s_setprio(1);
#pragma unroll
            for (int ts = 0; ts < 4; ts++) {
                f32x4 z = (f32x4){0.f, 0.f, 0.f, 0.f};
                z = __builtin_amdgcn_mfma_f32_16x16x32_bf16(aq0[qs], bk0[ts], z, 0, 0, 0);
                z = __builtin_amdgcn_mfma_f32_16x16x32_bf16(aq1[qs], bk1[ts], z, 0, 0, 0);
                sc[ts] = z;
            }
            __builtin_amdgcn_s_setprio(0);
#pragma unroll
            for (int ts = 0; ts < 4; ts++)
#pragma unroll
                for (int r = 0; r < 4; r++) {
                    float p = __builtin_amdgcn_exp2f(sc[ts][r]);   // scale folded into Q
                    lsum[qs][r] += p;
                    myP[(qs * 16 + qd * 4 + r) * 72 + ts * 16 + c] = f2bfbits(p);
                }
        }

        // P A-fragments (same-wave LDS readback; compiler inserts lgkmcnt)
#pragma unroll
        for (int qs = 0; qs < 2; qs++) {
            bf16x8 ap0 = ld_frag(&myP[(qs * 16 + c) * 72 + qd * 8]);
            bf16x8 ap1 = ld_frag(&myP[(qs * 16 + c) * 72 + 32 + qd * 8]);
            __builtin_amdgcn_s_setprio(1);
#pragma unroll
            for (int nt = 0; nt < 4; nt++) {
                acc[qs * 4 + nt] = __builtin_amdgcn_mfma_f32_16x16x32_bf16(ap0, bv0[nt], acc[qs * 4 + nt], 0, 0, 0);
                acc[qs * 4 + nt] = __builtin_amdgcn_mfma_f32_16x16x32_bf16(ap1, bv1[nt], acc[qs * 4 + nt], 0, 0, 0);
            }
            __builtin_amdgcn_s_setprio(0);
        }
    }

    // per-wave row-sum reduction across the 16 column lanes
#pragma unroll
    for (int off = 1; off < 16; off <<= 1)
#pragma unroll
        for (int qs = 0; qs < 2; qs++)
#pragma unroll
            for (int r = 0; r < 4; r++) lsum[qs][r] += __shfl_xor(lsum[qs][r], off);
    if (c == 0) {
#pragma unroll
        for (int qs = 0; qs < 2; qs++)
#pragma unroll
            for (int r = 0; r < 4; r++)
                l_all[w][qs * 16 + qd * 4 + r] = lsum[qs][r];
    }

    // tree-reduce acc over 8 waves; reduce buffer aliases Pl
    // slot = 2304 floats (9216 B) per wave: lane*36 (36%32=4 -> rotating banks)
    float* red = (float*)&Pl[0][0];
    __syncthreads();                              // all main loops + l writes done
    if (w >= 4) {
        float* rp = red + (w - 4) * 2304 + lane * 36;
#pragma unroll
        for (int i = 0; i < 8; i++) *reinterpret_cast<f32x4*>(rp + i * 4) = acc[i];
    }
    __syncthreads();
    if (w < 4) {
        float* rp = red + w * 2304 + lane * 36;
#pragma unroll
        for (int i = 0; i < 8; i++) acc[i] += *reinterpret_cast<const f32x4*>(rp + i * 4);
    }
    __syncthreads();
    if (w == 2 || w == 3) {
        float* rp = red + (w - 2) * 2304 + lane * 36;
#pragma unroll
        for (int i = 0; i < 8; i++) *reinterpret_cast<f32x4*>(rp + i * 4) = acc[i];
    }
    __syncthreads();
    if (w < 2) {
        float* rp = red + w * 2304 + lane * 36;
#pragma unroll
        for (int i = 0; i < 8; i++) acc[i] += *reinterpret_cast<const f32x4*>(rp + i * 4);
    }
    __syncthreads();
    if (w == 1) {
        float* rp = red + lane * 36;
#pragma unroll
        for (int i = 0; i < 8; i++) *reinterpret_cast<f32x4*>(rp + i * 4) = acc[i];
    }
    __syncthreads();
    if (w == 0) {
        float* rp = red + lane * 36;
#pragma unroll
        for (int i = 0; i < 8; i++) acc[i] += *reinterpret_cast<const f32x4*>(rp + i * 4);
#pragma unroll
        for (int qs = 0; qs < 2; qs++)
#pragma unroll
            for (int r = 0; r < 4; r++) {
                int q = qs * 16 + qd * 4 + r;
                float l = 0.f;
#pragma unroll
                for (int ww = 0; ww < 8; ww++) l += l_all[ww][q];
                float inv = 1.0f / l;
                size_t row = (size_t)(b << 12) + qbase + q;
#pragma unroll
                for (int nt = 0; nt < 4; nt++)
                    out[row * 64 + nt * 16 + c] = acc[qs * 4 + nt][r] * inv;
            }
    }
}

// ---------- launch ----------
extern "C" void kernel_launch(void* const* d_in, const int* in_sizes, int n_in,
                              void* d_out, int out_size, void* d_ws, size_t ws_size,
                              hipStream_t stream) {
    const float* emb = (const float*)d_in[0];
    const float* Wq  = (const float*)d_in[1];
    const float* bq  = (const float*)d_in[2];
    const float* Wk  = (const float*)d_in[3];
    const float* bk  = (const float*)d_in[4];
    const float* Wv  = (const float*)d_in[5];
    const float* bv  = (const float*)d_in[6];
    float* out = (float*)d_out;

    unsigned short* ws = (unsigned short*)d_ws;
    unsigned short* WtS = ws;                      // 192*1024
    unsigned short* Qb = ws + 192 * 1024;          // QTOT*64
    unsigned short* Kb = Qb + QTOT * 64;
    unsigned short* VT = Kb + QTOT * 64;           // total 6,684,672 B — always fits

    prep_weights<<<768, 256, 0, stream>>>(Wq, Wk, Wv, WtS);
    proj_cs<<<512, 256, 0, stream>>>(emb, WtS, bq, bk, bv, Qb, Kb, VT);
    attn<<<512, 512, 0, stream>>>(Qb, Kb, VT, out);
}

// Round 6
// 162.527 us; speedup vs baseline: 1.1125x; 1.1125x over previous
//
#include <hip/hip_runtime.h>

#define SEQ  4096
#define DMODEL 1024
#define QTOT 16384           // B*S
#define QSCALE 0.18033688011112042f   // (1/sqrt(64)) * log2(e), folded into Q

typedef __bf16 bf16x8 __attribute__((ext_vector_type(8)));
typedef unsigned short u16x8 __attribute__((ext_vector_type(8)));
typedef float f32x4 __attribute__((ext_vector_type(4)));

// ---------- helpers ----------
static __device__ __forceinline__ unsigned short f2bfbits(float f) {
    unsigned int u = __builtin_bit_cast(unsigned int, f);
    unsigned int lsb = (u >> 16) & 1u;
    u += 0x7fffu + lsb;                      // round-to-nearest-even
    return (unsigned short)(u >> 16);
}

static __device__ __forceinline__ bf16x8 ld_frag(const unsigned short* p) {
    uint4 u = *reinterpret_cast<const uint4*>(p);
    return __builtin_bit_cast(bf16x8, u);
}

// ---------- kernel 1: weights -> bf16, pre-swizzled into MFMA fragment order ----------
__global__ void prep_weights(const float* __restrict__ Wq,
                             const float* __restrict__ Wk,
                             const float* __restrict__ Wv,
                             unsigned short* __restrict__ WtS) {
    int o = blockIdx.x * 256 + threadIdx.x;      // 192*1024 total
    int f = o >> 9, q = o & 511;
    int lane = q >> 3, j = q & 7;
    int kc = f / 12, nt = f - kc * 12;
    int n = nt * 16 + (lane & 15);
    int k = kc * 32 + (lane >> 4) * 8 + j;
    float v;
    if (n < 64)       v = Wq[k * 64 + n];
    else if (n < 128) v = Wk[k * 64 + (n - 64)];
    else              v = Wv[k * 64 + (n - 128)];
    WtS[o] = f2bfbits(v);
}

// ---------- kernel 2: QKV projection, coalesced LDS-staged emb ----------
// grid 512 x 256 thr (4 waves). Block = 32 tokens, N=192, full K (no K-split).
// wave w: m = w&1 (16-token M-subtile), nh = w>>1 (6-of-12 nt slice). acc[6].
// emb staged through LDS in 4 mega-steps of K=256 (contiguous 1KB row-chunks,
// XOR-swizzled LDS, T14 early-issue). Weights: contiguous fragment loads with
// s+1 prefetch pipeline.
__global__ __launch_bounds__(256) void proj_cs(
        const float* __restrict__ emb, const unsigned short* __restrict__ WtS,
        const float* __restrict__ bq, const float* __restrict__ bk,
        const float* __restrict__ bv,
        unsigned short* __restrict__ Qb, unsigned short* __restrict__ Kb,
        unsigned short* __restrict__ VT) {
    __shared__ __align__(16) unsigned short Et[2][32 * 256];   // 2 x 16 KB

    const int tid = threadIdx.x;
    const int w = tid >> 6, lane = tid & 63;
    const int c = lane & 15, qd = lane >> 4;
    const int m = w & 1, nh = w >> 1;
    const int mbase = blockIdx.x * 32;

    f32x4 acc[6];
#pragma unroll
    for (int i = 0; i < 6; i++) acc[i] = (f32x4){0.f, 0.f, 0.f, 0.f};

    // this wave's weight-fragment base: nt = nh*6 + jj
    const unsigned short* wpB = WtS + nh * 3072 + lane * 8;

    // ---- prologue: stage mega 0 (rows w*8..w*8+7, contiguous 1KB per row) ----
    {
        float4 g[8];
#pragma unroll
        for (int rr = 0; rr < 8; rr++)
            g[rr] = *reinterpret_cast<const float4*>(
                emb + (size_t)(mbase + w * 8 + rr) * DMODEL + lane * 4);
#pragma unroll
        for (int rr = 0; rr < 8; rr++) {
            int row = w * 8 + rr;
            ushort4 p;
            p.x = f2bfbits(g[rr].x); p.y = f2bfbits(g[rr].y);
            p.z = f2bfbits(g[rr].z); p.w = f2bfbits(g[rr].w);
            int off = (lane * 8) ^ ((row & 7) << 4);           // byte off in 512B row
            *reinterpret_cast<ushort4*>(
                reinterpret_cast<char*>(&Et[0][0]) + row * 512 + off) = p;
        }
    }

    // weight fragments for s=0
    bf16x8 wc[6];
#pragma unroll
    for (int jj = 0; jj < 6; jj++) wc[jj] = ld_frag(wpB + jj * 512);

    __syncthreads();

    int cur = 0;
    for (int mega = 0; mega < 4; mega++) {
        // issue next mega's global loads early (in flight during the MFMAs)
        float4 g[8];
        if (mega < 3) {
#pragma unroll
            for (int rr = 0; rr < 8; rr++)
                g[rr] = *reinterpret_cast<const float4*>(
                    emb + (size_t)(mbase + w * 8 + rr) * DMODEL
                        + (mega + 1) * 256 + lane * 4);
        }

        // hoist all 8 A-fragments for this mega (conflict-free swizzled reads)
        const char* Eb = reinterpret_cast<const char*>(&Et[cur][0]);
        bf16x8 aq[8];
#pragma unroll
        for (int ks = 0; ks < 8; ks++) {
            int off = (ks * 64 + qd * 16) ^ ((c & 7) << 4);
            aq[ks] = ld_frag(reinterpret_cast<const unsigned short*>(
                Eb + (m * 16 + c) * 512 + off));
        }

        // 8 K-steps; weight pipeline one step ahead
#pragma unroll
        for (int ks = 0; ks < 8; ks++) {
            int s = mega * 8 + ks;
            bf16x8 wn[6];
            if (s < 31) {
#pragma unroll
                for (int jj = 0; jj < 6; jj++)
                    wn[jj] = ld_frag(wpB + (s + 1) * 6144 + jj * 512);
            } else {
#pragma unroll
                for (int jj = 0; jj < 6; jj++) wn[jj] = wc[jj];
            }
#pragma unroll
            for (int jj = 0; jj < 6; jj++)
                acc[jj] = __builtin_amdgcn_mfma_f32_16x16x32_bf16(aq[ks], wc[jj], acc[jj], 0, 0, 0);
#pragma unroll
            for (int jj = 0; jj < 6; jj++) wc[jj] = wn[jj];
        }

        // convert + write next buffer (vmcnt wait lands here, after compute)
        if (mega < 3) {
#pragma unroll
            for (int rr = 0; rr < 8; rr++) {
                int row = w * 8 + rr;
                ushort4 p;
                p.x = f2bfbits(g[rr].x); p.y = f2bfbits(g[rr].y);
                p.z = f2bfbits(g[rr].z); p.w = f2bfbits(g[rr].w);
                int off = (lane * 8) ^ ((row & 7) << 4);
                *reinterpret_cast<ushort4*>(
                    reinterpret_cast<char*>(&Et[cur ^ 1][0]) + row * 512 + off) = p;
            }
        }
        __syncthreads();
        cur ^= 1;
    }

    // ---- epilogue: bias + scale + bf16 store ----
#pragma unroll
    for (int jj = 0; jj < 6; jj++) {
        int n = (nh * 6 + jj) * 16 + c;
        float bias = (n < 64) ? bq[n] : (n < 128) ? bk[n - 64] : bv[n - 128];
        float fac = (n < 64) ? QSCALE : 1.0f;
#pragma unroll
        for (int r = 0; r < 4; r++) {
            int token = mbase + m * 16 + qd * 4 + r;
            unsigned short bits = f2bfbits((acc[jj][r] + bias) * fac);
            if (n < 64)        Qb[(size_t)token * 64 + n] = bits;
            else if (n < 128)  Kb[(size_t)token * 64 + (n - 64)] = bits;
            else {
                int bb = token >> 12, ss = token & 4095;
                VT[((size_t)bb * 64 + (n - 128)) * SEQ + ss] = bits;
            }
        }
    }
}

// ---------- kernel 3: barrier-free flash attention, t-split=2 ----------
// grid 512 = 4b x 64 q-blocks x 2 t-halves; XCD-pinned by (b,th) so each XCD's
// L2 holds one 512KB K/V half shared by its 64 blocks. 512 thr = 8 waves.
// Block owns 64 q-rows x t-half (2048); wave w owns t-slice [th*2048+w*256, +256).
// Round-3 inner body VERBATIM (64-row arithmetic intensity: 64 MFMA per 16
// loads/iter — round-5 showed halving q-rows instead halves intensity and
// LOSES). LDS 75.8KB + 96 VGPR -> 2 blocks/CU = 4 waves/SIMD (2x round-3 TLP).
// Partial (acc,l) per half -> finalize merges: out=(a0+a1)/(l0+l1). Exact:
// exp2 has no running max, so halves combine associatively.
__global__ __launch_bounds__(512, 2) void attn(
        const unsigned short* __restrict__ Qb, const unsigned short* __restrict__ Kb,
        const unsigned short* __restrict__ VT,
        float* __restrict__ accP, float* __restrict__ lsumP) {
    __shared__ __align__(16) unsigned short Pl[8][64 * 72];  // per-wave P [q][t]; aliased as reduce buf
    __shared__ float l_all[8][64];

    const int tid = threadIdx.x;
    const int w = tid >> 6, lane = tid & 63;
    const int c = lane & 15, qd = lane >> 4;
    // XCD pinning: blockIdx%8 = b*2 + th
    const int g3 = blockIdx.x & 7;
    const int b = g3 >> 1;
    const int th = g3 & 1;
    const int qblk = blockIdx.x >> 3;            // 0..63
    const int qbase = qblk * 64;
    const int tstart = th * 2048 + w * 256;

    // Q A-fragments (same for all 8 waves -> L1 broadcast), pre-scaled by QSCALE
    bf16x8 aq0[4], aq1[4];
#pragma unroll
    for (int qs = 0; qs < 4; qs++) {
        const unsigned short* Qp = Qb + ((size_t)(b << 12) + qbase + qs * 16 + c) * 64 + qd * 8;
        aq0[qs] = ld_frag(Qp);
        aq1[qs] = ld_frag(Qp + 32);
    }

    f32x4 acc[16];                               // [qsub][nt]
#pragma unroll
    for (int i = 0; i < 16; i++) acc[i] = (f32x4){0.f, 0.f, 0.f, 0.f};
    float lsum[4][4];                            // [qsub][r] per-lane partial
#pragma unroll
    for (int qs = 0; qs < 4; qs++)
#pragma unroll
        for (int r = 0; r < 4; r++) lsum[qs][r] = 0.f;

    unsigned short* myP = &Pl[w][0];

#pragma unroll 2
    for (int it = 0; it < 4; it++) {
        const int t0 = tstart + it * 64;
        const unsigned short* Kt = Kb + ((size_t)(b << 12) + t0) * 64;

        // K B-fragments straight from global
        bf16x8 bk0[4], bk1[4];
#pragma unroll
        for (int ts = 0; ts < 4; ts++) {
            bk0[ts] = ld_frag(Kt + (ts * 16 + c) * 64 + qd * 8);
            bk1[ts] = ld_frag(Kt + (ts * 16 + c) * 64 + 32 + qd * 8);
        }

        // scores -> exp2 -> P into per-wave LDS (no barrier)
#pragma unroll
        for (int qs = 0; qs < 4; qs++) {
            f32x4 sc[4];
#pragma unroll
            for (int ts = 0; ts < 4; ts++) {
                f32x4 z = (f32x4){0.f, 0.f, 0.f, 0.f};
                z = __builtin_amdgcn_mfma_f32_16x16x32_bf16(aq0[qs], bk0[ts], z, 0, 0, 0);
                z = __builtin_amdgcn_mfma_f32_16x16x32_bf16(aq1[qs], bk1[ts], z, 0, 0, 0);
                sc[ts] = z;
            }
#pragma unroll
            for (int ts = 0; ts < 4; ts++)
#pragma unroll
                for (int r = 0; r < 4; r++) {
                    float p = __builtin_amdgcn_exp2f(sc[ts][r]);   // scale folded into Q
                    lsum[qs][r] += p;
                    myP[(qs * 16 + qd * 4 + r) * 72 + ts * 16 + c] = f2bfbits(p);
                }
        }

        // V B-fragments straight from global (VT is [b][v][t])
        bf16x8 bv0[4], bv1[4];
#pragma unroll
        for (int nt = 0; nt < 4; nt++) {
            const unsigned short* Vp = VT + (((size_t)b * 64 + nt * 16 + c) << 12) + t0 + qd * 8;
            bv0[nt] = ld_frag(Vp);
            bv1[nt] = ld_frag(Vp + 32);
        }

        // P A-fragments (same-wave LDS readback; compiler inserts lgkmcnt)
#pragma unroll
        for (int qs = 0; qs < 4; qs++) {
            bf16x8 ap0 = ld_frag(&myP[(qs * 16 + c) * 72 + qd * 8]);
            bf16x8 ap1 = ld_frag(&myP[(qs * 16 + c) * 72 + 32 + qd * 8]);
#pragma unroll
            for (int nt = 0; nt < 4; nt++) {
                acc[qs * 4 + nt] = __builtin_amdgcn_mfma_f32_16x16x32_bf16(ap0, bv0[nt], acc[qs * 4 + nt], 0, 0, 0);
                acc[qs * 4 + nt] = __builtin_amdgcn_mfma_f32_16x16x32_bf16(ap1, bv1[nt], acc[qs * 4 + nt], 0, 0, 0);
            }
        }
    }

    // per-wave row-sum reduction across the 16 column lanes
#pragma unroll
    for (int off = 1; off < 16; off <<= 1)
#pragma unroll
        for (int qs = 0; qs < 4; qs++)
#pragma unroll
            for (int r = 0; r < 4; r++) lsum[qs][r] += __shfl_xor(lsum[qs][r], off);
    if (c == 0) {
#pragma unroll
        for (int qs = 0; qs < 4; qs++)
#pragma unroll
            for (int r = 0; r < 4; r++)
                l_all[w][qs * 16 + qd * 4 + r] = lsum[qs][r];
    }

    // tree-reduce acc over 8 waves; reduce buffer aliases Pl (slot = 17408 B)
    float* red = (float*)&Pl[0][0];
    __syncthreads();                              // all main loops + l writes done
    if (w >= 4) {
        float* rp = red + (w - 4) * 4352 + lane * 68;
#pragma unroll
        for (int i = 0; i < 16; i++) *reinterpret_cast<f32x4*>(rp + i * 4) = acc[i];
    }
    __syncthreads();
    if (w < 4) {
        float* rp = red + w * 4352 + lane * 68;
#pragma unroll
        for (int i = 0; i < 16; i++) acc[i] += *reinterpret_cast<const f32x4*>(rp + i * 4);
    }
    __syncthreads();
    if (w == 2 || w == 3) {
        float* rp = red + (w - 2) * 4352 + lane * 68;
#pragma unroll
        for (int i = 0; i < 16; i++) *reinterpret_cast<f32x4*>(rp + i * 4) = acc[i];
    }
    __syncthreads();
    if (w < 2) {
        float* rp = red + w * 4352 + lane * 68;
#pragma unroll
        for (int i = 0; i < 16; i++) acc[i] += *reinterpret_cast<const f32x4*>(rp + i * 4);
    }
    __syncthreads();
    if (w == 1) {
        float* rp = red + lane * 68;
#pragma unroll
        for (int i = 0; i < 16; i++) *reinterpret_cast<f32x4*>(rp + i * 4) = acc[i];
    }
    __syncthreads();
    if (w == 0) {
        float* rp = red + lane * 68;
#pragma unroll
        for (int i = 0; i < 16; i++) acc[i] += *reinterpret_cast<const f32x4*>(rp + i * 4);
        float* accOut = accP + (size_t)th * ((size_t)QTOT * 64);
        float* lOut   = lsumP + (size_t)th * QTOT;
#pragma unroll
        for (int qs = 0; qs < 4; qs++)
#pragma unroll
            for (int r = 0; r < 4; r++) {
                int q = qs * 16 + qd * 4 + r;
                float l = 0.f;
#pragma unroll
                for (int ww = 0; ww < 8; ww++) l += l_all[ww][q];
                size_t row = (size_t)(b << 12) + qbase + q;
                lOut[row] = l;
#pragma unroll
                for (int nt = 0; nt < 4; nt++)
                    accOut[row * 64 + nt * 16 + c] = acc[qs * 4 + nt][r];
            }
    }
}

// ---------- kernel 4: merge the two t-halves: out = (a0+a1)/(l0+l1) ----------
__global__ __launch_bounds__(256) void finalize(
        const float* __restrict__ accP, const float* __restrict__ lsumP,
        float* __restrict__ out) {
    int idx = blockIdx.x * 256 + threadIdx.x;    // float4 index, 0..QTOT*16-1
    int row = idx >> 4;
    float4 a0 = reinterpret_cast<const float4*>(accP)[idx];
    float4 a1 = reinterpret_cast<const float4*>(accP)[idx + QTOT * 16];
    float inv = 1.0f / (lsumP[row] + lsumP[row + QTOT]);
    float4 o;
    o.x = (a0.x + a1.x) * inv;
    o.y = (a0.y + a1.y) * inv;
    o.z = (a0.z + a1.z) * inv;
    o.w = (a0.w + a1.w) * inv;
    reinterpret_cast<float4*>(out)[idx] = o;
}

// ---------- launch ----------
extern "C" void kernel_launch(void* const* d_in, const int* in_sizes, int n_in,
                              void* d_out, int out_size, void* d_ws, size_t ws_size,
                              hipStream_t stream) {
    const float* emb = (const float*)d_in[0];
    const float* Wq  = (const float*)d_in[1];
    const float* bq  = (const float*)d_in[2];
    const float* Wk  = (const float*)d_in[3];
    const float* bk  = (const float*)d_in[4];
    const float* Wv  = (const float*)d_in[5];
    const float* bv  = (const float*)d_in[6];
    float* out = (float*)d_out;

    unsigned short* ws = (unsigned short*)d_ws;
    unsigned short* WtS = ws;                      // 384 KB
    unsigned short* Qb = ws + 192 * 1024;          // 2 MB
    unsigned short* Kb = Qb + QTOT * 64;           // 2 MB
    unsigned short* VT = Kb + QTOT * 64;           // 2 MB  (ends at 6,684,672 B)
    float* accP  = (float*)(VT + QTOT * 64);       // 2 x 4 MB partial acc
    float* lsumP = accP + (size_t)2 * QTOT * 64;   // 2 x 64 KB partial l
    // total ws use ≈ 15.2 MB (round-0 ran the 31.8 MB tier, so this fits)

    prep_weights<<<768, 256, 0, stream>>>(Wq, Wk, Wv, WtS);
    proj_cs<<<512, 256, 0, stream>>>(emb, WtS, bq, bk, bv, Qb, Kb, VT);
    attn<<<512, 512, 0, stream>>>(Qb, Kb, VT, accP, lsumP);
    finalize<<<1024, 256, 0, stream>>>(accP, lsumP, out);
}